// Round 1
// baseline (12489.706 us; speedup 1.0000x reference)
//
#include <hip/hip_runtime.h>
#include <cstdint>
#include <cstddef>

#define BB 2
#define NN 16384
#define SS 4096
#define KK 32
#define FIN 16
#define R2C 0.01f

// ---------------- FPS: one block per batch, points in registers ----------------
#define FPS_T 1024
#define PPT (NN / FPS_T) // 16

__global__ __launch_bounds__(FPS_T, 1) void fps_kernel(const float* __restrict__ pos,
                                                       int* __restrict__ idx_out) {
  const int b = blockIdx.x;
  const int t = threadIdx.x;
  const float* __restrict__ p = pos + (size_t)b * NN * 3;
  float px[PPT], py[PPT], pz[PPT], dmin[PPT];
#pragma unroll
  for (int j = 0; j < PPT; ++j) {
    const int i = j * FPS_T + t;
    px[j] = p[i * 3 + 0];
    py[j] = p[i * 3 + 1];
    pz[j] = p[i * 3 + 2];
    dmin[j] = 1e10f;
  }
  __shared__ float sL[3];
  __shared__ float swv[FPS_T / 64];
  __shared__ int swi[FPS_T / 64];
  if (t == 0) {
    sL[0] = p[0]; sL[1] = p[1]; sL[2] = p[2];
    idx_out[b * SS + 0] = 0;
  }
  __syncthreads();
  for (int it = 1; it < SS; ++it) {
    const float lx = sL[0], ly = sL[1], lz = sL[2];
    float bv = -1.0f;
    int bi = 0;
#pragma unroll
    for (int j = 0; j < PPT; ++j) {
      // exact np order: (dx*dx + dy*dy) + dz*dz, no FMA contraction
      const float dx = px[j] - lx;
      const float dy = py[j] - ly;
      const float dz = pz[j] - lz;
      const float d = __fadd_rn(__fadd_rn(__fmul_rn(dx, dx), __fmul_rn(dy, dy)), __fmul_rn(dz, dz));
      const float dm = fminf(dmin[j], d);
      dmin[j] = dm;
      // strictly greater keeps the earliest index (j ascending => index ascending)
      if (dm > bv) { bv = dm; bi = j * FPS_T + t; }
    }
    // wave argmax reduction, tie -> lowest index
#pragma unroll
    for (int off = 1; off < 64; off <<= 1) {
      const float ov = __shfl_xor(bv, off, 64);
      const int oi = __shfl_xor(bi, off, 64);
      if (ov > bv || (ov == bv && oi < bi)) { bv = ov; bi = oi; }
    }
    if ((t & 63) == 0) { swv[t >> 6] = bv; swi[t >> 6] = bi; }
    __syncthreads();
    if (t == 0) {
      float fv = swv[0]; int fi = swi[0];
#pragma unroll
      for (int w = 1; w < FPS_T / 64; ++w) {
        const float wv = swv[w]; const int wi = swi[w];
        if (wv > fv || (wv == fv && wi < fi)) { fv = wv; fi = wi; }
      }
      idx_out[b * SS + it] = fi;
      sL[0] = p[fi * 3 + 0];
      sL[1] = p[fi * 3 + 1];
      sL[2] = p[fi * 3 + 2];
    }
    __syncthreads();
  }
}

// ---------------- Ball query: one wave per centroid ----------------
__global__ __launch_bounds__(256) void ballq_kernel(const float* __restrict__ pos,
                                                    const int* __restrict__ idx,
                                                    int* __restrict__ nbr,
                                                    int* __restrict__ cnt,
                                                    float* __restrict__ outC,
                                                    float* __restrict__ outB) {
  const int cs = blockIdx.x * 4 + (threadIdx.x >> 6);
  const int lane = threadIdx.x & 63;
  const int b = cs >> 12;           // S = 4096
  const int s = cs & (SS - 1);
  const float* __restrict__ p = pos + (size_t)b * NN * 3;
  const int ci = idx[cs];
  const float cx = p[ci * 3 + 0], cy = p[ci * 3 + 1], cz = p[ci * 3 + 2];
  // remove_self_loops: global src b*N+i == global dst b*S+s  -> only b==0, i==s
  const int excl = (b == 0) ? s : -1;
  int count = 0;
  for (int tile = 0; tile < NN / 64; ++tile) {
    const int i = tile * 64 + lane;
    const float dx = cx - p[i * 3 + 0];
    const float dy = cy - p[i * 3 + 1];
    const float dz = cz - p[i * 3 + 2];
    const float d2 = __fadd_rn(__fadd_rn(__fmul_rn(dx, dx), __fmul_rn(dy, dy)), __fmul_rn(dz, dz));
    const bool in = (d2 <= R2C) && (i != excl);
    const unsigned long long m = __ballot(in);
    if (in) {
      const int rank = count + (int)__popcll(m & ((1ull << lane) - 1ull));
      if (rank < KK) nbr[cs * KK + rank] = i;
    }
    count += (int)__popcll(m);
    if (count >= KK) break;
  }
  if (lane == 0) {
    cnt[cs] = count < KK ? count : KK;
    outC[cs * 3 + 0] = cx;
    outC[cs * 3 + 1] = cy;
    outC[cs * 3 + 2] = cz;
    outB[cs] = (float)b;
  }
}

// ---------------- MLP + max: one block (128 thr) per centroid ----------------
#define EE 33
__global__ __launch_bounds__(128) void mlp_kernel(const float* __restrict__ x,
                                                  const float* __restrict__ pos,
                                                  const int* __restrict__ nbr,
                                                  const int* __restrict__ cnt,
                                                  const float* __restrict__ W1,
                                                  const float* __restrict__ b1,
                                                  const float* __restrict__ W2,
                                                  const float* __restrict__ b2,
                                                  const float* __restrict__ W3,
                                                  const float* __restrict__ b3,
                                                  const float* __restrict__ outC,
                                                  float* __restrict__ outX) {
  __shared__ float sW1[19][64];
  __shared__ float sb1[64];
  __shared__ float sW2[64][64];
  __shared__ float sb2[64];
  __shared__ float sb3[128];
  __shared__ float sF[EE][20];
  __shared__ float sH1[EE][64];
  __shared__ float sH2[EE][64];
  __shared__ int sValid[EE];

  const int cs = blockIdx.x;
  const int tid = threadIdx.x;
  const int b = cs >> 12;

  for (int i = tid; i < 19 * 64; i += 128) sW1[i / 64][i % 64] = W1[i];
  for (int i = tid; i < 64 * 64; i += 128) sW2[i >> 6][i & 63] = W2[i];
  if (tid < 64) { sb1[tid] = b1[tid]; sb2[tid] = b2[tid]; }
  sb3[tid] = b3[tid];
  // W3 column for this thread's output channel, kept in registers
  float w3c[64];
#pragma unroll
  for (int k = 0; k < 64; ++k) w3c[k] = W3[k * 128 + tid];

  if (tid < EE) {
    const float ccx = outC[cs * 3 + 0], ccy = outC[cs * 3 + 1], ccz = outC[cs * 3 + 2];
    int row;
    bool valid;
    if (tid < KK) {
      const int c = cnt[cs];
      valid = tid < c;
      const int j = valid ? nbr[cs * KK + tid] : 0;
      row = b * NN + j;
    } else {
      // PyG add_self_loops quirk: src is flat point index dflat = b*S+s = cs
      valid = true;
      row = cs;
    }
    for (int f = 0; f < FIN; ++f) sF[tid][f] = x[(size_t)row * FIN + f];
    sF[tid][16] = pos[(size_t)row * 3 + 0] - ccx;
    sF[tid][17] = pos[(size_t)row * 3 + 1] - ccy;
    sF[tid][18] = pos[(size_t)row * 3 + 2] - ccz;
    sValid[tid] = valid ? 1 : 0;
  }
  __syncthreads();
  // h1 = relu(feats @ W1 + b1)
  for (int tI = tid; tI < EE * 64; tI += 128) {
    const int e = tI >> 6, c = tI & 63;
    float acc = sb1[c];
#pragma unroll
    for (int k = 0; k < 19; ++k) acc += sF[e][k] * sW1[k][c];
    sH1[e][c] = fmaxf(acc, 0.0f);
  }
  __syncthreads();
  // h2 = relu(h1 @ W2 + b2)
  for (int tI = tid; tI < EE * 64; tI += 128) {
    const int e = tI >> 6, c = tI & 63;
    float acc = sb2[c];
#pragma unroll
    for (int k = 0; k < 64; ++k) acc += sH1[e][k] * sW2[k][c];
    sH2[e][c] = fmaxf(acc, 0.0f);
  }
  __syncthreads();
  // h3 = h2 @ W3 + b3, masked max over edges
  float mx = -1e30f;
  for (int e = 0; e < EE; ++e) {
    if (sValid[e]) {
      float acc = sb3[tid];
#pragma unroll
      for (int k = 0; k < 64; ++k) acc += sH2[e][k] * w3c[k];
      mx = fmaxf(mx, acc);
    }
  }
  outX[(size_t)cs * 128 + tid] = mx;
}

extern "C" void kernel_launch(void* const* d_in, const int* in_sizes, int n_in,
                              void* d_out, int out_size, void* d_ws, size_t ws_size,
                              hipStream_t stream) {
  const float* x = (const float*)d_in[0];
  const float* pos = (const float*)d_in[1];
  // d_in[2] = batch (recomputed analytically)
  const float* W1 = (const float*)d_in[3];
  const float* b1 = (const float*)d_in[4];
  const float* W2 = (const float*)d_in[5];
  const float* b2 = (const float*)d_in[6];
  const float* W3 = (const float*)d_in[7];
  const float* b3 = (const float*)d_in[8];

  float* out = (float*)d_out;
  float* outX = out;                               // [B*S,128]
  float* outC = out + (size_t)BB * SS * 128;       // [B*S,3]
  float* outB = outC + (size_t)BB * SS * 3;        // [B*S]

  int* idx = (int*)d_ws;                           // [B*S]
  int* nbr = idx + BB * SS;                        // [B*S,K]
  int* cnt = nbr + (size_t)BB * SS * KK;           // [B*S]

  hipLaunchKernelGGL(fps_kernel, dim3(BB), dim3(FPS_T), 0, stream, pos, idx);
  hipLaunchKernelGGL(ballq_kernel, dim3(BB * SS / 4), dim3(256), 0, stream,
                     pos, idx, nbr, cnt, outC, outB);
  hipLaunchKernelGGL(mlp_kernel, dim3(BB * SS), dim3(128), 0, stream,
                     x, pos, nbr, cnt, W1, b1, W2, b2, W3, b3, outC, outX);
}

// Round 2
// 9058.805 us; speedup vs baseline: 1.3787x; 1.3787x over previous
//
#include <hip/hip_runtime.h>
#include <cstdint>
#include <cstddef>

#define BB 2
#define NN 16384
#define SS 4096
#define KK 32
#define FIN 16
#define R2C 0.01f

// ---------------- FPS: one block per batch, points resident in VGPRs ----------------
#define FPS_T 512
#define PPT (NN / FPS_T) // 32
#define NWAVE (FPS_T / 64) // 8

__global__ __launch_bounds__(FPS_T, 1) void fps_kernel(const float* __restrict__ pos,
                                                       int* __restrict__ idx_out) {
  const int b = blockIdx.x;
  const int t = threadIdx.x;
  const float* __restrict__ p = pos + (size_t)b * NN * 3;
  float px[PPT], py[PPT], pz[PPT], dmin[PPT];
#pragma unroll
  for (int j = 0; j < PPT; ++j) {
    const int i = j * FPS_T + t;
    px[j] = p[i * 3 + 0];
    py[j] = p[i * 3 + 1];
    pz[j] = p[i * 3 + 2];
    dmin[j] = 1e10f;
  }
  __shared__ float2 sWin[2][NWAVE]; // (value, index-as-bits), double-buffered
  if (t == 0) idx_out[b * SS + 0] = 0;
  float lx = p[0], ly = p[1], lz = p[2];

  for (int it = 1; it < SS; ++it) {
    float bv = -1.0f;
    int bj = 0;
#pragma unroll
    for (int j = 0; j < PPT; ++j) {
      // exact np order: (dx*dx + dy*dy) + dz*dz, no FMA contraction
      const float dx = px[j] - lx;
      const float dy = py[j] - ly;
      const float dz = pz[j] - lz;
      const float d = __fadd_rn(__fadd_rn(__fmul_rn(dx, dx), __fmul_rn(dy, dy)), __fmul_rn(dz, dz));
      const float dm = fminf(dmin[j], d);
      dmin[j] = dm;
      // strictly greater keeps earliest j (ascending j => ascending global index)
      if (dm > bv) { bv = dm; bj = j; }
    }
    int bi = (bj * FPS_T) | t; // global point index of this thread's best

    // wave-level argmax butterfly, tie -> lowest index
#pragma unroll
    for (int off = 1; off < 64; off <<= 1) {
      const float ov = __shfl_xor(bv, off, 64);
      const int oi = __shfl_xor(bi, off, 64);
      if (ov > bv || (ov == bv && oi < bi)) { bv = ov; bi = oi; }
    }
    const int buf = it & 1;
    if ((t & 63) == 0) sWin[buf][t >> 6] = make_float2(bv, __int_as_float(bi));
    __syncthreads(); // the ONLY barrier per iteration (double buffer handles WAR)

    // every wave redundantly reduces the NWAVE winners -> all threads learn fi
    float2 e = sWin[buf][t & (NWAVE - 1)];
    float fv = e.x;
    int fi = __float_as_int(e.y);
#pragma unroll
    for (int off = 1; off < NWAVE; off <<= 1) {
      const float ov = __shfl_xor(fv, off, 64);
      const int oi = __shfl_xor(fi, off, 64);
      if (ov > fv || (ov == fv && oi < fi)) { fv = ov; fi = oi; }
    }
    if (t == 0) idx_out[b * SS + it] = fi;
    // all threads fetch winner coords in parallel (L2 broadcast, no serial thread-0 path)
    lx = p[fi * 3 + 0];
    ly = p[fi * 3 + 1];
    lz = p[fi * 3 + 2];
  }
}

// ---------------- Ball query: one wave per centroid ----------------
__global__ __launch_bounds__(256) void ballq_kernel(const float* __restrict__ pos,
                                                    const int* __restrict__ idx,
                                                    int* __restrict__ nbr,
                                                    int* __restrict__ cnt,
                                                    float* __restrict__ outC,
                                                    float* __restrict__ outB) {
  const int cs = blockIdx.x * 4 + (threadIdx.x >> 6);
  const int lane = threadIdx.x & 63;
  const int b = cs >> 12;           // S = 4096
  const int s = cs & (SS - 1);
  const float* __restrict__ p = pos + (size_t)b * NN * 3;
  const int ci = idx[cs];
  const float cx = p[ci * 3 + 0], cy = p[ci * 3 + 1], cz = p[ci * 3 + 2];
  // remove_self_loops: global src b*N+i == global dst b*S+s  -> only b==0, i==s
  const int excl = (b == 0) ? s : -1;
  int count = 0;
  for (int tile = 0; tile < NN / 64; ++tile) {
    const int i = tile * 64 + lane;
    const float dx = cx - p[i * 3 + 0];
    const float dy = cy - p[i * 3 + 1];
    const float dz = cz - p[i * 3 + 2];
    const float d2 = __fadd_rn(__fadd_rn(__fmul_rn(dx, dx), __fmul_rn(dy, dy)), __fmul_rn(dz, dz));
    const bool in = (d2 <= R2C) && (i != excl);
    const unsigned long long m = __ballot(in);
    if (in) {
      const int rank = count + (int)__popcll(m & ((1ull << lane) - 1ull));
      if (rank < KK) nbr[cs * KK + rank] = i;
    }
    count += (int)__popcll(m);
    if (count >= KK) break;
  }
  if (lane == 0) {
    cnt[cs] = count < KK ? count : KK;
    outC[cs * 3 + 0] = cx;
    outC[cs * 3 + 1] = cy;
    outC[cs * 3 + 2] = cz;
    outB[cs] = (float)b;
  }
}

// ---------------- MLP + max: one block (128 thr) per centroid ----------------
#define EE 33
__global__ __launch_bounds__(128) void mlp_kernel(const float* __restrict__ x,
                                                  const float* __restrict__ pos,
                                                  const int* __restrict__ nbr,
                                                  const int* __restrict__ cnt,
                                                  const float* __restrict__ W1,
                                                  const float* __restrict__ b1,
                                                  const float* __restrict__ W2,
                                                  const float* __restrict__ b2,
                                                  const float* __restrict__ W3,
                                                  const float* __restrict__ b3,
                                                  const float* __restrict__ outC,
                                                  float* __restrict__ outX) {
  __shared__ float sW1[19][64];
  __shared__ float sb1[64];
  __shared__ float sW2[64][64];
  __shared__ float sb2[64];
  __shared__ float sb3[128];
  __shared__ float sF[EE][20];
  __shared__ float sH1[EE][64];
  __shared__ float sH2[EE][64];
  __shared__ int sValid[EE];

  const int cs = blockIdx.x;
  const int tid = threadIdx.x;
  const int b = cs >> 12;

  for (int i = tid; i < 19 * 64; i += 128) sW1[i / 64][i % 64] = W1[i];
  for (int i = tid; i < 64 * 64; i += 128) sW2[i >> 6][i & 63] = W2[i];
  if (tid < 64) { sb1[tid] = b1[tid]; sb2[tid] = b2[tid]; }
  sb3[tid] = b3[tid];
  // W3 column for this thread's output channel, kept in registers
  float w3c[64];
#pragma unroll
  for (int k = 0; k < 64; ++k) w3c[k] = W3[k * 128 + tid];

  if (tid < EE) {
    const float ccx = outC[cs * 3 + 0], ccy = outC[cs * 3 + 1], ccz = outC[cs * 3 + 2];
    int row;
    bool valid;
    if (tid < KK) {
      const int c = cnt[cs];
      valid = tid < c;
      const int j = valid ? nbr[cs * KK + tid] : 0;
      row = b * NN + j;
    } else {
      // PyG add_self_loops quirk: src is flat point index dflat = b*S+s = cs
      valid = true;
      row = cs;
    }
    for (int f = 0; f < FIN; ++f) sF[tid][f] = x[(size_t)row * FIN + f];
    sF[tid][16] = pos[(size_t)row * 3 + 0] - ccx;
    sF[tid][17] = pos[(size_t)row * 3 + 1] - ccy;
    sF[tid][18] = pos[(size_t)row * 3 + 2] - ccz;
    sValid[tid] = valid ? 1 : 0;
  }
  __syncthreads();
  // h1 = relu(feats @ W1 + b1)
  for (int tI = tid; tI < EE * 64; tI += 128) {
    const int e = tI >> 6, c = tI & 63;
    float acc = sb1[c];
#pragma unroll
    for (int k = 0; k < 19; ++k) acc += sF[e][k] * sW1[k][c];
    sH1[e][c] = fmaxf(acc, 0.0f);
  }
  __syncthreads();
  // h2 = relu(h1 @ W2 + b2)
  for (int tI = tid; tI < EE * 64; tI += 128) {
    const int e = tI >> 6, c = tI & 63;
    float acc = sb2[c];
#pragma unroll
    for (int k = 0; k < 64; ++k) acc += sH1[e][k] * sW2[k][c];
    sH2[e][c] = fmaxf(acc, 0.0f);
  }
  __syncthreads();
  // h3 = h2 @ W3 + b3, masked max over edges
  float mx = -1e30f;
  for (int e = 0; e < EE; ++e) {
    if (sValid[e]) {
      float acc = sb3[tid];
#pragma unroll
      for (int k = 0; k < 64; ++k) acc += sH2[e][k] * w3c[k];
      mx = fmaxf(mx, acc);
    }
  }
  outX[(size_t)cs * 128 + tid] = mx;
}

extern "C" void kernel_launch(void* const* d_in, const int* in_sizes, int n_in,
                              void* d_out, int out_size, void* d_ws, size_t ws_size,
                              hipStream_t stream) {
  const float* x = (const float*)d_in[0];
  const float* pos = (const float*)d_in[1];
  // d_in[2] = batch (recomputed analytically)
  const float* W1 = (const float*)d_in[3];
  const float* b1 = (const float*)d_in[4];
  const float* W2 = (const float*)d_in[5];
  const float* b2 = (const float*)d_in[6];
  const float* W3 = (const float*)d_in[7];
  const float* b3 = (const float*)d_in[8];

  float* out = (float*)d_out;
  float* outX = out;                               // [B*S,128]
  float* outC = out + (size_t)BB * SS * 128;       // [B*S,3]
  float* outB = outC + (size_t)BB * SS * 3;        // [B*S]

  int* idx = (int*)d_ws;                           // [B*S]
  int* nbr = idx + BB * SS;                        // [B*S,K]
  int* cnt = nbr + (size_t)BB * SS * KK;           // [B*S]

  hipLaunchKernelGGL(fps_kernel, dim3(BB), dim3(FPS_T), 0, stream, pos, idx);
  hipLaunchKernelGGL(ballq_kernel, dim3(BB * SS / 4), dim3(256), 0, stream,
                     pos, idx, nbr, cnt, outC, outB);
  hipLaunchKernelGGL(mlp_kernel, dim3(BB * SS), dim3(128), 0, stream,
                     x, pos, nbr, cnt, W1, b1, W2, b2, W3, b3, outC, outX);
}